// Round 1
// baseline (469.343 us; speedup 1.0000x reference)
//
#include <hip/hip_runtime.h>
#include <hip/hip_bf16.h>

#define BB 8
#define NN 2048
#define CC 256
#define DKK 64
#define DVV 256
#define COFF 60.0f

typedef __attribute__((ext_vector_type(8))) short bf16x8;
typedef __attribute__((ext_vector_type(4))) float f32x4;

#define MFMA16 __builtin_amdgcn_mfma_f32_16x16x32_bf16

static __device__ __forceinline__ unsigned short f2bf(float f) {
    unsigned int u = __float_as_uint(f);
    u += 0x7fffu + ((u >> 16) & 1u);
    return (unsigned short)(u >> 16);
}
static __device__ __forceinline__ float bf2f(unsigned short h) {
    return __uint_as_float(((unsigned int)h) << 16);
}

// ---------------- kernel 0: gather Wq|Wk|Wv transposed into Wt[c][384] -----
__global__ void k_wt(const float* __restrict__ Wq, const float* __restrict__ Wk,
                     const float* __restrict__ Wv, float* __restrict__ Wt) {
    int idx = blockIdx.x * 256 + threadIdx.x;
    if (idx >= CC * 384) return;
    int c = idx / 384, d = idx % 384;
    float v;
    if (d < 64)       v = Wq[d * CC + c];
    else if (d < 128) v = Wk[(d - 64) * CC + c];
    else              v = Wv[(d - 128) * CC + c];
    Wt[idx] = v;  // idx == c*384 + d
}

// ---------------- kernel 1: projections (fp32), write split-bf16 q/k, vT ---
// block: 192 threads, 16 rows of x; each thread owns output cols d and d+192.
__global__ __launch_bounds__(192) void k_proj(
    const float* __restrict__ x, const float* __restrict__ Wt,
    unsigned short* __restrict__ qh, unsigned short* __restrict__ ql,
    unsigned short* __restrict__ kh, unsigned short* __restrict__ kl,
    unsigned short* __restrict__ vT)
{
    __shared__ float xs[16 * 256];
    int row0 = blockIdx.x * 16;
    const float4* xin = (const float4*)(x + (size_t)row0 * 256);
    float4* xs4 = (float4*)xs;
    for (int i = threadIdx.x; i < 1024; i += 192) xs4[i] = xin[i];
    __syncthreads();
    int d = threadIdx.x;  // 0..191
    float acc0[16], acc1[16];
    #pragma unroll
    for (int r = 0; r < 16; ++r) { acc0[r] = 0.f; acc1[r] = 0.f; }
    for (int c0 = 0; c0 < 256; c0 += 4) {
        const float* wp = Wt + c0 * 384 + d;
        float w00 = wp[0],   w01 = wp[384], w02 = wp[768],  w03 = wp[1152];
        float w10 = wp[192], w11 = wp[576], w12 = wp[960],  w13 = wp[1344];
        #pragma unroll
        for (int r = 0; r < 16; ++r) {
            float4 xv = *(const float4*)(xs + r * 256 + c0);
            acc0[r] = fmaf(xv.x, w00, acc0[r]);
            acc0[r] = fmaf(xv.y, w01, acc0[r]);
            acc0[r] = fmaf(xv.z, w02, acc0[r]);
            acc0[r] = fmaf(xv.w, w03, acc0[r]);
            acc1[r] = fmaf(xv.x, w10, acc1[r]);
            acc1[r] = fmaf(xv.y, w11, acc1[r]);
            acc1[r] = fmaf(xv.z, w12, acc1[r]);
            acc1[r] = fmaf(xv.w, w13, acc1[r]);
        }
    }
    #pragma unroll
    for (int r = 0; r < 16; ++r) {
        int bn = row0 + r;
        int b = bn >> 11, n = bn & 2047;
        {   // column d: q (0..63) | k (64..127) | v (128..191)
            float v = acc0[r];
            unsigned short h = f2bf(v);
            if (d < 64) {
                qh[(size_t)bn * 64 + d] = h;
                ql[(size_t)bn * 64 + d] = f2bf(v - bf2f(h));
            } else if (d < 128) {
                kh[(size_t)bn * 64 + (d - 64)] = h;
                kl[(size_t)bn * 64 + (d - 64)] = f2bf(v - bf2f(h));
            } else {
                vT[((size_t)b * 256 + (d - 128)) * 2048 + n] = h;
            }
        }
        {   // column d+192: always v (rows 64..255)
            vT[((size_t)b * 256 + (d + 64)) * 2048 + n] = f2bf(acc1[r]);
        }
    }
}

// ---------------- kernel 2: column sums cs[m] = sum_n exp(S[n,m]-60) -------
// A = k-tile (M dim = m), B = q-tile (N dim = n).  grid (32, 8), 4 waves.
__global__ __launch_bounds__(256) void k_colsum(
    const unsigned short* __restrict__ qh, const unsigned short* __restrict__ ql,
    const unsigned short* __restrict__ kh, const unsigned short* __restrict__ kl,
    float* __restrict__ cs)
{
    int b = blockIdx.y;
    int wave = threadIdx.x >> 6, lane = threadIdx.x & 63;
    int m0 = blockIdx.x * 64 + wave * 16;
    int arow = m0 + (lane & 15);
    int kc = (lane >> 4) * 8;
    const unsigned short* khp = kh + ((size_t)b * 2048 + arow) * 64 + kc;
    const unsigned short* klp = kl + ((size_t)b * 2048 + arow) * 64 + kc;
    bf16x8 ah0 = *(const bf16x8*)khp;
    bf16x8 ah1 = *(const bf16x8*)(khp + 32);
    bf16x8 al0 = *(const bf16x8*)klp;
    bf16x8 al1 = *(const bf16x8*)(klp + 32);
    float ssum[4] = {0.f, 0.f, 0.f, 0.f};
    for (int nt = 0; nt < 2048; nt += 16) {
        int brow = nt + (lane & 15);
        const unsigned short* qhp = qh + ((size_t)b * 2048 + brow) * 64 + kc;
        const unsigned short* qlp = ql + ((size_t)b * 2048 + brow) * 64 + kc;
        bf16x8 bh0 = *(const bf16x8*)qhp;
        bf16x8 bh1 = *(const bf16x8*)(qhp + 32);
        bf16x8 bl0 = *(const bf16x8*)qlp;
        bf16x8 bl1 = *(const bf16x8*)(qlp + 32);
        f32x4 a0 = {0.f, 0.f, 0.f, 0.f}, a1 = {0.f, 0.f, 0.f, 0.f};
        a0 = MFMA16(ah0, bh0, a0, 0, 0, 0);
        a0 = MFMA16(ah1, bh1, a0, 0, 0, 0);
        a1 = MFMA16(ah0, bl0, a1, 0, 0, 0);
        a1 = MFMA16(ah1, bl1, a1, 0, 0, 0);
        a1 = MFMA16(al0, bh0, a1, 0, 0, 0);
        a1 = MFMA16(al1, bh1, a1, 0, 0, 0);
        #pragma unroll
        for (int r = 0; r < 4; ++r)
            ssum[r] += __expf((a0[r] + a1[r]) - COFF);
    }
    #pragma unroll
    for (int r = 0; r < 4; ++r) {
        float v = ssum[r];
        v += __shfl_xor(v, 1, 16);
        v += __shfl_xor(v, 2, 16);
        v += __shfl_xor(v, 4, 16);
        v += __shfl_xor(v, 8, 16);
        ssum[r] = v;
    }
    if ((lane & 15) == 0) {
        int mrow = m0 + (lane >> 4) * 4;
        #pragma unroll
        for (int r = 0; r < 4; ++r) cs[(size_t)b * 2048 + mrow + r] = ssum[r];
    }
}

// ---------------- kernel 3: flash pass: P = exp(S-60)/cs, out = P·v / Σ_m P
// grid (32, 8), 4 waves; wave w owns rows n0+16w .. +16.
__global__ __launch_bounds__(256) void k_attn(
    const unsigned short* __restrict__ qh, const unsigned short* __restrict__ ql,
    const unsigned short* __restrict__ kh, const unsigned short* __restrict__ kl,
    const unsigned short* __restrict__ vT, const float* __restrict__ cs,
    float* __restrict__ out)
{
    __shared__ float cs_s[2048];
    __shared__ __align__(16) short pbuf[4][16][64];
    int b = blockIdx.y;
    int wave = threadIdx.x >> 6, lane = threadIdx.x & 63;
    int n0 = blockIdx.x * 64 + wave * 16;
    for (int i = threadIdx.x; i < 2048; i += 256) cs_s[i] = cs[(size_t)b * 2048 + i];
    int arow = n0 + (lane & 15);
    int kc = (lane >> 4) * 8;
    const unsigned short* qhp = qh + ((size_t)b * 2048 + arow) * 64 + kc;
    const unsigned short* qlp = ql + ((size_t)b * 2048 + arow) * 64 + kc;
    bf16x8 ah0 = *(const bf16x8*)qhp;
    bf16x8 ah1 = *(const bf16x8*)(qhp + 32);
    bf16x8 al0 = *(const bf16x8*)qlp;
    bf16x8 al1 = *(const bf16x8*)(qlp + 32);
    f32x4 accv[16];
    #pragma unroll
    for (int i = 0; i < 16; ++i) accv[i] = (f32x4){0.f, 0.f, 0.f, 0.f};
    float rs[4] = {0.f, 0.f, 0.f, 0.f};
    __syncthreads();
    for (int m0 = 0; m0 < 2048; m0 += 64) {
        #pragma unroll
        for (int g = 0; g < 4; ++g) {
            int mrow = m0 + g * 16 + (lane & 15);
            const unsigned short* khp = kh + ((size_t)b * 2048 + mrow) * 64 + kc;
            const unsigned short* klp = kl + ((size_t)b * 2048 + mrow) * 64 + kc;
            bf16x8 bh0 = *(const bf16x8*)khp;
            bf16x8 bh1 = *(const bf16x8*)(khp + 32);
            bf16x8 bl0 = *(const bf16x8*)klp;
            bf16x8 bl1 = *(const bf16x8*)(klp + 32);
            f32x4 s0 = {0.f, 0.f, 0.f, 0.f}, s1 = {0.f, 0.f, 0.f, 0.f};
            s0 = MFMA16(ah0, bh0, s0, 0, 0, 0);
            s0 = MFMA16(ah1, bh1, s0, 0, 0, 0);
            s1 = MFMA16(ah0, bl0, s1, 0, 0, 0);
            s1 = MFMA16(ah1, bl1, s1, 0, 0, 0);
            s1 = MFMA16(al0, bh0, s1, 0, 0, 0);
            s1 = MFMA16(al1, bh1, s1, 0, 0, 0);
            float rcs = 1.0f / cs_s[m0 + g * 16 + (lane & 15)];
            #pragma unroll
            for (int r = 0; r < 4; ++r) {
                float p = __expf((s0[r] + s1[r]) - COFF) * rcs;
                rs[r] += p;
                pbuf[wave][(lane >> 4) * 4 + r][g * 16 + (lane & 15)] = (short)f2bf(p);
            }
        }
        __syncthreads();
        bf16x8 p0 = *(const bf16x8*)(&pbuf[wave][lane & 15][kc]);
        bf16x8 p1 = *(const bf16x8*)(&pbuf[wave][lane & 15][32 + kc]);
        #pragma unroll
        for (int dg = 0; dg < 16; ++dg) {
            int drow = dg * 16 + (lane & 15);
            const unsigned short* vp = vT + ((size_t)b * 256 + drow) * 2048 + m0 + kc;
            bf16x8 v0 = *(const bf16x8*)vp;
            bf16x8 v1 = *(const bf16x8*)(vp + 32);
            accv[dg] = MFMA16(p0, v0, accv[dg], 0, 0, 0);
            accv[dg] = MFMA16(p1, v1, accv[dg], 0, 0, 0);
        }
        __syncthreads();
    }
    #pragma unroll
    for (int r = 0; r < 4; ++r) {
        float v = rs[r];
        v += __shfl_xor(v, 1, 16);
        v += __shfl_xor(v, 2, 16);
        v += __shfl_xor(v, 4, 16);
        v += __shfl_xor(v, 8, 16);
        rs[r] = 1.0f / (1e-9f + v);
    }
    #pragma unroll
    for (int r = 0; r < 4; ++r) {
        int n = n0 + (lane >> 4) * 4 + r;
        float scale = rs[r];
        #pragma unroll
        for (int dg = 0; dg < 16; ++dg) {
            out[((size_t)b * 2048 + n) * 256 + dg * 16 + (lane & 15)] = accv[dg][r] * scale;
        }
    }
}

extern "C" void kernel_launch(void* const* d_in, const int* in_sizes, int n_in,
                              void* d_out, int out_size, void* d_ws, size_t ws_size,
                              hipStream_t stream) {
    (void)in_sizes; (void)n_in; (void)out_size; (void)ws_size;
    const float* x  = (const float*)d_in[0];
    const float* Wq = (const float*)d_in[1];
    const float* Wk = (const float*)d_in[2];
    const float* Wv = (const float*)d_in[3];
    float* out = (float*)d_out;

    char* ws = (char*)d_ws;
    size_t off = 0;
    float* Wt = (float*)(ws + off);            off += (size_t)384 * 256 * 4;
    unsigned short* qh = (unsigned short*)(ws + off); off += (size_t)BB * NN * DKK * 2;
    unsigned short* ql = (unsigned short*)(ws + off); off += (size_t)BB * NN * DKK * 2;
    unsigned short* kh = (unsigned short*)(ws + off); off += (size_t)BB * NN * DKK * 2;
    unsigned short* kl = (unsigned short*)(ws + off); off += (size_t)BB * NN * DKK * 2;
    unsigned short* vT = (unsigned short*)(ws + off); off += (size_t)BB * DVV * NN * 2;
    float* cs = (float*)(ws + off);            off += (size_t)BB * NN * 4;

    hipLaunchKernelGGL(k_wt,     dim3(384),        dim3(256), 0, stream, Wq, Wk, Wv, Wt);
    hipLaunchKernelGGL(k_proj,   dim3(BB * NN / 16), dim3(192), 0, stream, x, Wt, qh, ql, kh, kl, vT);
    hipLaunchKernelGGL(k_colsum, dim3(NN / 64, BB), dim3(256), 0, stream, qh, ql, kh, kl, cs);
    hipLaunchKernelGGL(k_attn,   dim3(NN / 64, BB), dim3(256), 0, stream, qh, ql, kh, kl, vT, cs, out);
}

// Round 2
// 253.262 us; speedup vs baseline: 1.8532x; 1.8532x over previous
//
#include <hip/hip_runtime.h>
#include <hip/hip_bf16.h>

#define BB 8
#define NN 2048
#define CC 256
#define DKK 64
#define DVV 256
#define COFF 60.0f

typedef __attribute__((ext_vector_type(8))) short bf16x8;
typedef __attribute__((ext_vector_type(4))) float f32x4;

#define MFMA16 __builtin_amdgcn_mfma_f32_16x16x32_bf16

static __device__ __forceinline__ unsigned short f2bf(float f) {
    unsigned int u = __float_as_uint(f);
    u += 0x7fffu + ((u >> 16) & 1u);
    return (unsigned short)(u >> 16);
}
static __device__ __forceinline__ float bf2f(unsigned short h) {
    return __uint_as_float(((unsigned int)h) << 16);
}

// async global->LDS, 16B per lane; LDS dest = base + lane*16
static __device__ __forceinline__ void g2l16(const unsigned short* g, unsigned short* l) {
    __builtin_amdgcn_global_load_lds(
        (const __attribute__((address_space(1))) void*)g,
        (__attribute__((address_space(3))) void*)l, 16, 0, 0);
}

// ---------------- kernel 0: gather Wq|Wk|Wv transposed into Wt[c][384] -----
__global__ void k_wt(const float* __restrict__ Wq, const float* __restrict__ Wk,
                     const float* __restrict__ Wv, float* __restrict__ Wt) {
    int idx = blockIdx.x * 256 + threadIdx.x;
    if (idx >= CC * 384) return;
    int c = idx / 384, d = idx % 384;
    float v;
    if (d < 64)       v = Wq[d * CC + c];
    else if (d < 128) v = Wk[(d - 64) * CC + c];
    else              v = Wv[(d - 128) * CC + c];
    Wt[idx] = v;
}

// ---------------- kernel 1: projections (fp32), write split-bf16 q/k, vT ---
// kh/kl rows are XOR-swizzled per 8-elem chunk by (row&7); vT swizzled per
// 64-m window by (d&7) -- so global_load_lds images are bank-conflict-free.
__global__ __launch_bounds__(192) void k_proj(
    const float* __restrict__ x, const float* __restrict__ Wt,
    unsigned short* __restrict__ qh, unsigned short* __restrict__ ql,
    unsigned short* __restrict__ kh, unsigned short* __restrict__ kl,
    unsigned short* __restrict__ vT)
{
    __shared__ float xs[16 * 256];
    int row0 = blockIdx.x * 16;
    const float4* xin = (const float4*)(x + (size_t)row0 * 256);
    float4* xs4 = (float4*)xs;
    for (int i = threadIdx.x; i < 1024; i += 192) xs4[i] = xin[i];
    __syncthreads();
    int d = threadIdx.x;  // 0..191
    float acc0[16], acc1[16];
    #pragma unroll
    for (int r = 0; r < 16; ++r) { acc0[r] = 0.f; acc1[r] = 0.f; }
    for (int c0 = 0; c0 < 256; c0 += 4) {
        const float* wp = Wt + c0 * 384 + d;
        float w00 = wp[0],   w01 = wp[384], w02 = wp[768],  w03 = wp[1152];
        float w10 = wp[192], w11 = wp[576], w12 = wp[960],  w13 = wp[1344];
        #pragma unroll
        for (int r = 0; r < 16; ++r) {
            float4 xv = *(const float4*)(xs + r * 256 + c0);
            acc0[r] = fmaf(xv.x, w00, acc0[r]);
            acc0[r] = fmaf(xv.y, w01, acc0[r]);
            acc0[r] = fmaf(xv.z, w02, acc0[r]);
            acc0[r] = fmaf(xv.w, w03, acc0[r]);
            acc1[r] = fmaf(xv.x, w10, acc1[r]);
            acc1[r] = fmaf(xv.y, w11, acc1[r]);
            acc1[r] = fmaf(xv.z, w12, acc1[r]);
            acc1[r] = fmaf(xv.w, w13, acc1[r]);
        }
    }
    #pragma unroll
    for (int r = 0; r < 16; ++r) {
        int bn = row0 + r;
        int b = bn >> 11, n = bn & 2047;
        {
            float v = acc0[r];
            unsigned short h = f2bf(v);
            if (d < 64) {
                qh[(size_t)bn * 64 + d] = h;
                ql[(size_t)bn * 64 + d] = f2bf(v - bf2f(h));
            } else if (d < 128) {
                int dd = d - 64;
                int dsw = ((((dd >> 3) ^ bn) & 7) << 3) | (dd & 7);
                kh[(size_t)bn * 64 + dsw] = h;
                kl[(size_t)bn * 64 + dsw] = f2bf(v - bf2f(h));
            } else {
                int dvd = d - 128;
                int nsw = (n & ~63) | ((((n >> 3) ^ dvd) & 7) << 3) | (n & 7);
                vT[((size_t)b * 256 + dvd) * 2048 + nsw] = h;
            }
        }
        {
            int dvd = d + 64;
            int nsw = (n & ~63) | ((((n >> 3) ^ dvd) & 7) << 3) | (n & 7);
            vT[((size_t)b * 256 + dvd) * 2048 + nsw] = f2bf(acc1[r]);
        }
    }
}

// ---------------- kernel 2: column sums cs[m] = sum_n exp(S[n,m]-60) -------
// 16 waves: wave = (i = m-subtile 0..3, j = n-quarter 0..3). grid (32,8).
__global__ __launch_bounds__(1024) void k_colsum(
    const unsigned short* __restrict__ qh, const unsigned short* __restrict__ ql,
    const unsigned short* __restrict__ kh, const unsigned short* __restrict__ kl,
    float* __restrict__ cs)
{
    __shared__ float csbuf[4][64];
    int tid = threadIdx.x;
    int w = tid >> 6, lane = tid & 63;
    int t = lane & 15, qd = lane >> 4;
    int b = blockIdx.y, m0 = blockIdx.x * 64;
    int i = w >> 2, j = w & 3;

    int arow = m0 + i * 16 + t;
    int off0 = ((qd ^ (arow & 7)) << 3);            // swizzled k-chunk (c=0)
    const unsigned short* kbh = kh + ((size_t)b * 2048 + arow) * 64;
    const unsigned short* kbl = kl + ((size_t)b * 2048 + arow) * 64;
    bf16x8 ah0 = *(const bf16x8*)(kbh + off0);
    bf16x8 ah1 = *(const bf16x8*)(kbh + (off0 ^ 32));
    bf16x8 al0 = *(const bf16x8*)(kbl + off0);
    bf16x8 al1 = *(const bf16x8*)(kbl + (off0 ^ 32));

    float ssum[4] = {0.f, 0.f, 0.f, 0.f};
    for (int itn = 0; itn < 32; ++itn) {
        int brow = j * 512 + itn * 16 + t;
        const unsigned short* qbh = qh + ((size_t)b * 2048 + brow) * 64 + qd * 8;
        const unsigned short* qbl = ql + ((size_t)b * 2048 + brow) * 64 + qd * 8;
        bf16x8 bh0 = *(const bf16x8*)qbh;
        bf16x8 bh1 = *(const bf16x8*)(qbh + 32);
        bf16x8 bl0 = *(const bf16x8*)qbl;
        bf16x8 bl1 = *(const bf16x8*)(qbl + 32);
        f32x4 a0 = {0.f,0.f,0.f,0.f}, a1 = {0.f,0.f,0.f,0.f};
        a0 = MFMA16(ah0, bh0, a0, 0, 0, 0);
        a0 = MFMA16(ah1, bh1, a0, 0, 0, 0);
        a1 = MFMA16(ah0, bl0, a1, 0, 0, 0);
        a1 = MFMA16(ah1, bl1, a1, 0, 0, 0);
        a1 = MFMA16(al0, bh0, a1, 0, 0, 0);
        a1 = MFMA16(al1, bh1, a1, 0, 0, 0);
        #pragma unroll
        for (int r = 0; r < 4; ++r)
            ssum[r] += __expf((a0[r] + a1[r]) - COFF);
    }
    #pragma unroll
    for (int r = 0; r < 4; ++r) {
        float v = ssum[r];
        v += __shfl_xor(v, 1, 16);
        v += __shfl_xor(v, 2, 16);
        v += __shfl_xor(v, 4, 16);
        v += __shfl_xor(v, 8, 16);
        ssum[r] = v;
    }
    if (t == 0) {
        #pragma unroll
        for (int r = 0; r < 4; ++r) csbuf[j][i * 16 + qd * 4 + r] = ssum[r];
    }
    __syncthreads();
    if (tid < 64)
        cs[(size_t)b * 2048 + m0 + tid] =
            csbuf[0][tid] + csbuf[1][tid] + csbuf[2][tid] + csbuf[3][tid];
}

// ---------------- kernel 3: flash pass. 16 waves/block, grid (32,8). -------
// QK role:  wave = (i = n-subtile 0..3, j = m-subtile 0..3) -> one 16x16 S-tile
// PV role:  wave = (i2 = n-half 0..1, j8 = dv-pair 0..7) -> 32n x 32dv, accv 16 VGPR
// k/v tiles staged to LDS via global_load_lds (double-buffered, swizzled layouts)
__global__ __launch_bounds__(1024) void k_attn(
    const unsigned short* __restrict__ qh, const unsigned short* __restrict__ ql,
    const unsigned short* __restrict__ kh, const unsigned short* __restrict__ kl,
    const unsigned short* __restrict__ vT, const float* __restrict__ cs,
    float* __restrict__ out)
{
    __shared__ __align__(16) unsigned short kbuf[2][128 * 64];  // rows 0-63 kh, 64-127 kl
    __shared__ __align__(16) unsigned short vbuf[2][256 * 64];
    __shared__ __align__(16) unsigned short pP[64 * 72];        // padded stride 72
    __shared__ float cs_s[2048];
    __shared__ float rsbuf[4][64];

    int tid = threadIdx.x;
    int w = tid >> 6, lane = tid & 63;
    int t = lane & 15, qd = lane >> 4;
    int b = blockIdx.y;
    int n0 = blockIdx.x * 64;
    int i = w >> 2, j = w & 3;       // QK roles
    int i2 = w >> 3, j8 = w & 7;     // PV roles

    for (int u = tid; u < 2048; u += 1024) cs_s[u] = cs[(size_t)b * 2048 + u];

    // persistent q A-frags (rows n0 + i*16 + t), plain layout
    const unsigned short* qbh = qh + ((size_t)b * 2048 + n0 + i * 16 + t) * 64 + qd * 8;
    const unsigned short* qbl = ql + ((size_t)b * 2048 + n0 + i * 16 + t) * 64 + qd * 8;
    bf16x8 ah0 = *(const bf16x8*)qbh;
    bf16x8 ah1 = *(const bf16x8*)(qbh + 32);
    bf16x8 al0 = *(const bf16x8*)qbl;
    bf16x8 al1 = *(const bf16x8*)(qbl + 32);

    // staging source addresses (per lane). Each wave: 2 v-chunks + 1 k-chunk.
    int lr = lane >> 3, lc = (lane & 7) << 3;
    const unsigned short* vsrc0 = vT + ((size_t)b * 256 + w * 16 + lr) * 2048 + lc;
    const unsigned short* vsrc1 = vT + ((size_t)b * 256 + w * 16 + 8 + lr) * 2048 + lc;
    const unsigned short* karr = (w < 8) ? kh : kl;
    const unsigned short* ksrc = karr + ((size_t)b * 2048 + (w & 7) * 8 + lr) * 64 + lc;
    unsigned short* vdst0 = &vbuf[0][0] + w * 1024;
    unsigned short* vdst1 = vdst0 + 512;
    unsigned short* kdst = &kbuf[0][0] + w * 512;

#define STAGE(bufi, m0s) do { \
        g2l16(vsrc0 + (m0s), vdst0 + (bufi) * 16384); \
        g2l16(vsrc1 + (m0s), vdst1 + (bufi) * 16384); \
        g2l16(ksrc + (size_t)(m0s) * 64, kdst + (bufi) * 8192); \
    } while (0)

    f32x4 accv[2][2];
    accv[0][0] = (f32x4){0.f,0.f,0.f,0.f}; accv[0][1] = (f32x4){0.f,0.f,0.f,0.f};
    accv[1][0] = (f32x4){0.f,0.f,0.f,0.f}; accv[1][1] = (f32x4){0.f,0.f,0.f,0.f};
    float rs[4] = {0.f, 0.f, 0.f, 0.f};

    STAGE(0, 0);

    for (int it = 0; it < 32; ++it) {
        __syncthreads();                       // tile it ready; pP of it-1 consumed
        int cur = it & 1;
        int m0 = it * 64;
        // ---- QK: one 16x16 S-tile per wave ----
        {
            int mr = j * 16 + t;
            int off0 = ((qd ^ (t & 7)) << 3);  // mr&7 == t&7
            const unsigned short* khrow = &kbuf[cur][mr * 64];
            const unsigned short* klrow = &kbuf[cur][(64 + mr) * 64];
            bf16x8 bh0 = *(const bf16x8*)(khrow + off0);
            bf16x8 bh1 = *(const bf16x8*)(khrow + (off0 ^ 32));
            bf16x8 bl0 = *(const bf16x8*)(klrow + off0);
            bf16x8 bl1 = *(const bf16x8*)(klrow + (off0 ^ 32));
            f32x4 s0 = {0.f,0.f,0.f,0.f}, s1 = {0.f,0.f,0.f,0.f};
            s0 = MFMA16(ah0, bh0, s0, 0, 0, 0);
            s0 = MFMA16(ah1, bh1, s0, 0, 0, 0);
            s1 = MFMA16(ah0, bl0, s1, 0, 0, 0);
            s1 = MFMA16(ah1, bl1, s1, 0, 0, 0);
            s1 = MFMA16(al0, bh0, s1, 0, 0, 0);
            s1 = MFMA16(al1, bh1, s1, 0, 0, 0);
            float rcs = 1.0f / cs_s[m0 + j * 16 + t];
            unsigned short* prow = pP + (size_t)(i * 16 + qd * 4) * 72 + j * 16 + t;
            #pragma unroll
            for (int r = 0; r < 4; ++r) {
                float p = __expf((s0[r] + s1[r]) - COFF) * rcs;
                rs[r] += p;
                prow[r * 72] = f2bf(p);
            }
        }
        if (it + 1 < 32) STAGE((it + 1) & 1, m0 + 64);
        __syncthreads();                       // pP ready (also drains prefetch)
        // ---- PV: 32n x 32dv per wave over 64 m ----
        {
            const unsigned short* vb = &vbuf[cur][0];
            #pragma unroll
            for (int c = 0; c < 2; ++c) {
                bf16x8 pa0 = *(const bf16x8*)(pP + (size_t)((2*i2 + 0) * 16 + t) * 72 + c * 32 + qd * 8);
                bf16x8 pa1 = *(const bf16x8*)(pP + (size_t)((2*i2 + 1) * 16 + t) * 72 + c * 32 + qd * 8);
                int ch = (((c * 4 + qd) ^ (t & 7)) << 3);
                bf16x8 vb0 = *(const bf16x8*)(vb + ((2*j8 + 0) * 16 + t) * 64 + ch);
                bf16x8 vb1 = *(const bf16x8*)(vb + ((2*j8 + 1) * 16 + t) * 64 + ch);
                accv[0][0] = MFMA16(pa0, vb0, accv[0][0], 0, 0, 0);
                accv[0][1] = MFMA16(pa0, vb1, accv[0][1], 0, 0, 0);
                accv[1][0] = MFMA16(pa1, vb0, accv[1][0], 0, 0, 0);
                accv[1][1] = MFMA16(pa1, vb1, accv[1][1], 0, 0, 0);
            }
        }
    }
#undef STAGE

    // row-sum reduce: within 16-lane groups, then across j-waves via LDS
    #pragma unroll
    for (int r = 0; r < 4; ++r) {
        float v = rs[r];
        v += __shfl_xor(v, 1, 16);
        v += __shfl_xor(v, 2, 16);
        v += __shfl_xor(v, 4, 16);
        v += __shfl_xor(v, 8, 16);
        rs[r] = v;
    }
    if (t == 0) {
        #pragma unroll
        for (int r = 0; r < 4; ++r) rsbuf[j][i * 16 + qd * 4 + r] = rs[r];
    }
    __syncthreads();

    #pragma unroll
    for (int s2 = 0; s2 < 2; ++s2) {
        #pragma unroll
        for (int r = 0; r < 4; ++r) {
            int nl = (2 * i2 + s2) * 16 + qd * 4 + r;
            float tot = rsbuf[0][nl] + rsbuf[1][nl] + rsbuf[2][nl] + rsbuf[3][nl];
            float sc = 1.0f / (1e-9f + tot);
            size_t orow = ((size_t)b * 2048 + n0 + nl) * 256;
            out[orow + (2 * j8 + 0) * 16 + t] = accv[s2][0][r] * sc;
            out[orow + (2 * j8 + 1) * 16 + t] = accv[s2][1][r] * sc;
        }
    }
}

extern "C" void kernel_launch(void* const* d_in, const int* in_sizes, int n_in,
                              void* d_out, int out_size, void* d_ws, size_t ws_size,
                              hipStream_t stream) {
    (void)in_sizes; (void)n_in; (void)out_size; (void)ws_size;
    const float* x  = (const float*)d_in[0];
    const float* Wq = (const float*)d_in[1];
    const float* Wk = (const float*)d_in[2];
    const float* Wv = (const float*)d_in[3];
    float* out = (float*)d_out;

    char* ws = (char*)d_ws;
    size_t off = 0;
    float* Wt = (float*)(ws + off);            off += (size_t)384 * 256 * 4;
    unsigned short* qh = (unsigned short*)(ws + off); off += (size_t)BB * NN * DKK * 2;
    unsigned short* ql = (unsigned short*)(ws + off); off += (size_t)BB * NN * DKK * 2;
    unsigned short* kh = (unsigned short*)(ws + off); off += (size_t)BB * NN * DKK * 2;
    unsigned short* kl = (unsigned short*)(ws + off); off += (size_t)BB * NN * DKK * 2;
    unsigned short* vT = (unsigned short*)(ws + off); off += (size_t)BB * DVV * NN * 2;
    float* cs = (float*)(ws + off);            off += (size_t)BB * NN * 4;

    hipLaunchKernelGGL(k_wt,     dim3(384),          dim3(256),  0, stream, Wq, Wk, Wv, Wt);
    hipLaunchKernelGGL(k_proj,   dim3(BB * NN / 16), dim3(192),  0, stream, x, Wt, qh, ql, kh, kl, vT);
    hipLaunchKernelGGL(k_colsum, dim3(NN / 64, BB),  dim3(1024), 0, stream, qh, ql, kh, kl, cs);
    hipLaunchKernelGGL(k_attn,   dim3(NN / 64, BB),  dim3(1024), 0, stream, qh, ql, kh, kl, vT, cs, out);
}

// Round 3
// 226.490 us; speedup vs baseline: 2.0722x; 1.1182x over previous
//
#include <hip/hip_runtime.h>
#include <hip/hip_bf16.h>

#define BB 8
#define NN 2048
#define CC 256
#define DKK 64
#define DVV 256
#define COFF 60.0f

typedef __attribute__((ext_vector_type(8))) short bf16x8;
typedef __attribute__((ext_vector_type(4))) float f32x4;

#define MFMA16 __builtin_amdgcn_mfma_f32_16x16x32_bf16

static __device__ __forceinline__ unsigned short f2bf(float f) {
    unsigned int u = __float_as_uint(f);
    u += 0x7fffu + ((u >> 16) & 1u);
    return (unsigned short)(u >> 16);
}
static __device__ __forceinline__ float bf2f(unsigned short h) {
    return __uint_as_float(((unsigned int)h) << 16);
}

// async global->LDS, 16B per lane; LDS dest = base + lane*16
static __device__ __forceinline__ void g2l16(const unsigned short* g, unsigned short* l) {
    __builtin_amdgcn_global_load_lds(
        (const __attribute__((address_space(1))) void*)g,
        (__attribute__((address_space(3))) void*)l, 16, 0, 0);
}

// ---------------- kernel 0: split W into bf16 h/l, rows: q(0..63)|k|v -----
__global__ void k_wt(const float* __restrict__ Wq, const float* __restrict__ Wk,
                     const float* __restrict__ Wv,
                     unsigned short* __restrict__ Wh, unsigned short* __restrict__ Wl) {
    int idx = blockIdx.x * 256 + threadIdx.x;   // 384*256 total
    if (idx >= 384 * 256) return;
    int d = idx >> 8, c = idx & 255;
    float w;
    if (d < 64)       w = Wq[d * 256 + c];
    else if (d < 128) w = Wk[(d - 64) * 256 + c];
    else              w = Wv[(d - 128) * 256 + c];
    unsigned short h = f2bf(w);
    Wh[idx] = h;
    Wl[idx] = f2bf(w - bf2f(h));
}

// ---------------- kernel 0b: split x into bf16 h/l ------------------------
__global__ __launch_bounds__(256) void k_split(
    const float* __restrict__ x,
    unsigned short* __restrict__ xh, unsigned short* __restrict__ xl) {
    int tid = blockIdx.x * 256 + threadIdx.x;   // 524288 threads, 8 elems each
    const float4* xp = (const float4*)x + tid * 2;
    float4 a = xp[0], b = xp[1];
    float v[8] = {a.x, a.y, a.z, a.w, b.x, b.y, b.z, b.w};
    ushort4 h4[2], l4[2];
    #pragma unroll
    for (int i = 0; i < 8; ++i) {
        unsigned short h = f2bf(v[i]);
        ((unsigned short*)h4)[i] = h;
        ((unsigned short*)l4)[i] = f2bf(v[i] - bf2f(h));
    }
    ((ushort4*)xh)[tid * 2]     = h4[0];
    ((ushort4*)xh)[tid * 2 + 1] = h4[1];
    ((ushort4*)xl)[tid * 2]     = l4[0];
    ((ushort4*)xl)[tid * 2 + 1] = l4[1];
}

// ---------------- kernel 1a: v projection (single-pass bf16 MFMA) ---------
// grid 1024 (one 16-row n-tile per block), 4 waves; wave w: dt = 8+4w..8+4w+3
__global__ __launch_bounds__(256) void k_vproj(
    const unsigned short* __restrict__ xh, const unsigned short* __restrict__ Wh,
    unsigned short* __restrict__ vT)
{
    int w = threadIdx.x >> 6, lane = threadIdx.x & 63;
    int t = lane & 15, qd = lane >> 4;
    int n0 = blockIdx.x * 16;
    int bn = n0 + t;
    bf16x8 bfr[8];
    const unsigned short* bp = xh + (size_t)bn * 256 + qd * 8;
    #pragma unroll
    for (int c = 0; c < 8; ++c) bfr[c] = *(const bf16x8*)(bp + c * 32);
    #pragma unroll
    for (int k = 0; k < 4; ++k) {
        int dt = 8 + w * 4 + k;
        const unsigned short* ap = Wh + (size_t)(dt * 16 + t) * 256 + qd * 8;
        f32x4 acc = {0.f, 0.f, 0.f, 0.f};
        #pragma unroll
        for (int c = 0; c < 8; ++c) {
            bf16x8 a = *(const bf16x8*)(ap + c * 32);
            acc = MFMA16(a, bfr[c], acc, 0, 0, 0);
        }
        int b = bn >> 11, n = bn & 2047;
        #pragma unroll
        for (int r = 0; r < 4; ++r) {
            int dvd = dt * 16 + qd * 4 + r - 128;
            int nsw = (n & ~63) | ((((n >> 3) ^ dvd) & 7) << 3) | (n & 7);
            vT[((size_t)b * 256 + dvd) * 2048 + nsw] = f2bf(acc[r]);
        }
    }
}

// ---------------- kernel 1b: q/k projection (3-pass split-bf16 MFMA) ------
// grid 1024, 4 waves; wave w: dt = 2w, 2w+1  (d = 0..127)
__global__ __launch_bounds__(256) void k_qkproj(
    const unsigned short* __restrict__ xh, const unsigned short* __restrict__ xl,
    const unsigned short* __restrict__ Wh, const unsigned short* __restrict__ Wl,
    unsigned short* __restrict__ qh, unsigned short* __restrict__ ql,
    unsigned short* __restrict__ kh, unsigned short* __restrict__ kl)
{
    int w = threadIdx.x >> 6, lane = threadIdx.x & 63;
    int t = lane & 15, qd = lane >> 4;
    int n0 = blockIdx.x * 16;
    int bn = n0 + t;
    bf16x8 bh[8], bl[8];
    const unsigned short* bph = xh + (size_t)bn * 256 + qd * 8;
    const unsigned short* bpl = xl + (size_t)bn * 256 + qd * 8;
    #pragma unroll
    for (int c = 0; c < 8; ++c) {
        bh[c] = *(const bf16x8*)(bph + c * 32);
        bl[c] = *(const bf16x8*)(bpl + c * 32);
    }
    #pragma unroll
    for (int k = 0; k < 2; ++k) {
        int dt = w * 2 + k;
        const unsigned short* aph = Wh + (size_t)(dt * 16 + t) * 256 + qd * 8;
        const unsigned short* apl = Wl + (size_t)(dt * 16 + t) * 256 + qd * 8;
        f32x4 acc = {0.f, 0.f, 0.f, 0.f};
        #pragma unroll
        for (int c = 0; c < 8; ++c) {
            bf16x8 a = *(const bf16x8*)(aph + c * 32);
            bf16x8 al = *(const bf16x8*)(apl + c * 32);
            acc = MFMA16(a, bh[c], acc, 0, 0, 0);
            acc = MFMA16(a, bl[c], acc, 0, 0, 0);
            acc = MFMA16(al, bh[c], acc, 0, 0, 0);
        }
        ushort4 h4, l4;
        #pragma unroll
        for (int r = 0; r < 4; ++r) {
            unsigned short h = f2bf(acc[r]);
            ((unsigned short*)&h4)[r] = h;
            ((unsigned short*)&l4)[r] = f2bf(acc[r] - bf2f(h));
        }
        int dbase = dt * 16 + qd * 4;
        if (dbase < 64) {
            *(ushort4*)(qh + (size_t)bn * 64 + dbase) = h4;
            *(ushort4*)(ql + (size_t)bn * 64 + dbase) = l4;
        } else {
            int dd0 = dbase - 64;
            int sw = ((((dd0 >> 3) ^ bn) & 7) << 3) | (dd0 & 7);
            *(ushort4*)(kh + (size_t)bn * 64 + sw) = h4;
            *(ushort4*)(kl + (size_t)bn * 64 + sw) = l4;
        }
    }
}

// ---------------- kernel 2: column sums cs[m] = sum_n exp(S[n,m]-60) -------
__global__ __launch_bounds__(1024) void k_colsum(
    const unsigned short* __restrict__ qh, const unsigned short* __restrict__ ql,
    const unsigned short* __restrict__ kh, const unsigned short* __restrict__ kl,
    float* __restrict__ cs)
{
    __shared__ float csbuf[4][64];
    int tid = threadIdx.x;
    int w = tid >> 6, lane = tid & 63;
    int t = lane & 15, qd = lane >> 4;
    int b = blockIdx.y, m0 = blockIdx.x * 64;
    int i = w >> 2, j = w & 3;

    int arow = m0 + i * 16 + t;
    int off0 = ((qd ^ (arow & 7)) << 3);
    const unsigned short* kbh = kh + ((size_t)b * 2048 + arow) * 64;
    const unsigned short* kbl = kl + ((size_t)b * 2048 + arow) * 64;
    bf16x8 ah0 = *(const bf16x8*)(kbh + off0);
    bf16x8 ah1 = *(const bf16x8*)(kbh + (off0 ^ 32));
    bf16x8 al0 = *(const bf16x8*)(kbl + off0);
    bf16x8 al1 = *(const bf16x8*)(kbl + (off0 ^ 32));

    float ssum[4] = {0.f, 0.f, 0.f, 0.f};
    for (int itn = 0; itn < 32; ++itn) {
        int brow = j * 512 + itn * 16 + t;
        const unsigned short* qbh = qh + ((size_t)b * 2048 + brow) * 64 + qd * 8;
        const unsigned short* qbl = ql + ((size_t)b * 2048 + brow) * 64 + qd * 8;
        bf16x8 bh0 = *(const bf16x8*)qbh;
        bf16x8 bh1 = *(const bf16x8*)(qbh + 32);
        bf16x8 bl0 = *(const bf16x8*)qbl;
        bf16x8 bl1 = *(const bf16x8*)(qbl + 32);
        f32x4 a0 = {0.f,0.f,0.f,0.f}, a1 = {0.f,0.f,0.f,0.f};
        a0 = MFMA16(ah0, bh0, a0, 0, 0, 0);
        a0 = MFMA16(ah1, bh1, a0, 0, 0, 0);
        a1 = MFMA16(ah0, bl0, a1, 0, 0, 0);
        a1 = MFMA16(ah1, bl1, a1, 0, 0, 0);
        a1 = MFMA16(al0, bh0, a1, 0, 0, 0);
        a1 = MFMA16(al1, bh1, a1, 0, 0, 0);
        #pragma unroll
        for (int r = 0; r < 4; ++r)
            ssum[r] += __expf((a0[r] + a1[r]) - COFF);
    }
    #pragma unroll
    for (int r = 0; r < 4; ++r) {
        float v = ssum[r];
        v += __shfl_xor(v, 1, 16);
        v += __shfl_xor(v, 2, 16);
        v += __shfl_xor(v, 4, 16);
        v += __shfl_xor(v, 8, 16);
        ssum[r] = v;
    }
    if (t == 0) {
        #pragma unroll
        for (int r = 0; r < 4; ++r) csbuf[j][i * 16 + qd * 4 + r] = ssum[r];
    }
    __syncthreads();
    if (tid < 64)
        cs[(size_t)b * 2048 + m0 + tid] =
            csbuf[0][tid] + csbuf[1][tid] + csbuf[2][tid] + csbuf[3][tid];
}

// ---------------- kernel 3: flash pass. 16 waves/block, grid (32,8). -------
__global__ __launch_bounds__(1024) void k_attn(
    const unsigned short* __restrict__ qh, const unsigned short* __restrict__ ql,
    const unsigned short* __restrict__ kh, const unsigned short* __restrict__ kl,
    const unsigned short* __restrict__ vT, const float* __restrict__ cs,
    float* __restrict__ out)
{
    __shared__ __align__(16) unsigned short kbuf[2][128 * 64];
    __shared__ __align__(16) unsigned short vbuf[2][256 * 64];
    __shared__ __align__(16) unsigned short pP[64 * 72];
    __shared__ float cs_s[2048];
    __shared__ float rsbuf[4][64];

    int tid = threadIdx.x;
    int w = tid >> 6, lane = tid & 63;
    int t = lane & 15, qd = lane >> 4;
    int b = blockIdx.y;
    int n0 = blockIdx.x * 64;
    int i = w >> 2, j = w & 3;
    int i2 = w >> 3, j8 = w & 7;

    for (int u = tid; u < 2048; u += 1024) cs_s[u] = cs[(size_t)b * 2048 + u];

    const unsigned short* qbh = qh + ((size_t)b * 2048 + n0 + i * 16 + t) * 64 + qd * 8;
    const unsigned short* qbl = ql + ((size_t)b * 2048 + n0 + i * 16 + t) * 64 + qd * 8;
    bf16x8 ah0 = *(const bf16x8*)qbh;
    bf16x8 ah1 = *(const bf16x8*)(qbh + 32);
    bf16x8 al0 = *(const bf16x8*)qbl;
    bf16x8 al1 = *(const bf16x8*)(qbl + 32);

    int lr = lane >> 3, lc = (lane & 7) << 3;
    const unsigned short* vsrc0 = vT + ((size_t)b * 256 + w * 16 + lr) * 2048 + lc;
    const unsigned short* vsrc1 = vT + ((size_t)b * 256 + w * 16 + 8 + lr) * 2048 + lc;
    const unsigned short* karr = (w < 8) ? kh : kl;
    const unsigned short* ksrc = karr + ((size_t)b * 2048 + (w & 7) * 8 + lr) * 64 + lc;
    unsigned short* vdst0 = &vbuf[0][0] + w * 1024;
    unsigned short* vdst1 = vdst0 + 512;
    unsigned short* kdst = &kbuf[0][0] + w * 512;

#define STAGE(bufi, m0s) do { \
        g2l16(vsrc0 + (m0s), vdst0 + (bufi) * 16384); \
        g2l16(vsrc1 + (m0s), vdst1 + (bufi) * 16384); \
        g2l16(ksrc + (size_t)(m0s) * 64, kdst + (bufi) * 8192); \
    } while (0)

    f32x4 accv[2][2];
    accv[0][0] = (f32x4){0.f,0.f,0.f,0.f}; accv[0][1] = (f32x4){0.f,0.f,0.f,0.f};
    accv[1][0] = (f32x4){0.f,0.f,0.f,0.f}; accv[1][1] = (f32x4){0.f,0.f,0.f,0.f};
    float rs[4] = {0.f, 0.f, 0.f, 0.f};

    STAGE(0, 0);

    for (int it = 0; it < 32; ++it) {
        __syncthreads();
        int cur = it & 1;
        int m0 = it * 64;
        {
            int mr = j * 16 + t;
            int off0 = ((qd ^ (t & 7)) << 3);
            const unsigned short* khrow = &kbuf[cur][mr * 64];
            const unsigned short* klrow = &kbuf[cur][(64 + mr) * 64];
            bf16x8 bh0 = *(const bf16x8*)(khrow + off0);
            bf16x8 bh1 = *(const bf16x8*)(khrow + (off0 ^ 32));
            bf16x8 bl0 = *(const bf16x8*)(klrow + off0);
            bf16x8 bl1 = *(const bf16x8*)(klrow + (off0 ^ 32));
            f32x4 s0 = {0.f,0.f,0.f,0.f}, s1 = {0.f,0.f,0.f,0.f};
            s0 = MFMA16(ah0, bh0, s0, 0, 0, 0);
            s0 = MFMA16(ah1, bh1, s0, 0, 0, 0);
            s1 = MFMA16(ah0, bl0, s1, 0, 0, 0);
            s1 = MFMA16(ah1, bl1, s1, 0, 0, 0);
            s1 = MFMA16(al0, bh0, s1, 0, 0, 0);
            s1 = MFMA16(al1, bh1, s1, 0, 0, 0);
            float rcs = 1.0f / cs_s[m0 + j * 16 + t];
            unsigned short* prow = pP + (size_t)(i * 16 + qd * 4) * 72 + j * 16 + t;
            #pragma unroll
            for (int r = 0; r < 4; ++r) {
                float p = __expf((s0[r] + s1[r]) - COFF) * rcs;
                rs[r] += p;
                prow[r * 72] = f2bf(p);
            }
        }
        if (it + 1 < 32) STAGE((it + 1) & 1, m0 + 64);
        __syncthreads();
        {
            const unsigned short* vb = &vbuf[cur][0];
            #pragma unroll
            for (int c = 0; c < 2; ++c) {
                bf16x8 pa0 = *(const bf16x8*)(pP + (size_t)((2*i2 + 0) * 16 + t) * 72 + c * 32 + qd * 8);
                bf16x8 pa1 = *(const bf16x8*)(pP + (size_t)((2*i2 + 1) * 16 + t) * 72 + c * 32 + qd * 8);
                int ch = (((c * 4 + qd) ^ (t & 7)) << 3);
                bf16x8 vb0 = *(const bf16x8*)(vb + ((2*j8 + 0) * 16 + t) * 64 + ch);
                bf16x8 vb1 = *(const bf16x8*)(vb + ((2*j8 + 1) * 16 + t) * 64 + ch);
                accv[0][0] = MFMA16(pa0, vb0, accv[0][0], 0, 0, 0);
                accv[0][1] = MFMA16(pa0, vb1, accv[0][1], 0, 0, 0);
                accv[1][0] = MFMA16(pa1, vb0, accv[1][0], 0, 0, 0);
                accv[1][1] = MFMA16(pa1, vb1, accv[1][1], 0, 0, 0);
            }
        }
    }
#undef STAGE

    #pragma unroll
    for (int r = 0; r < 4; ++r) {
        float v = rs[r];
        v += __shfl_xor(v, 1, 16);
        v += __shfl_xor(v, 2, 16);
        v += __shfl_xor(v, 4, 16);
        v += __shfl_xor(v, 8, 16);
        rs[r] = v;
    }
    if (t == 0) {
        #pragma unroll
        for (int r = 0; r < 4; ++r) rsbuf[j][i * 16 + qd * 4 + r] = rs[r];
    }
    __syncthreads();

    #pragma unroll
    for (int s2 = 0; s2 < 2; ++s2) {
        #pragma unroll
        for (int r = 0; r < 4; ++r) {
            int nl = (2 * i2 + s2) * 16 + qd * 4 + r;
            float tot = rsbuf[0][nl] + rsbuf[1][nl] + rsbuf[2][nl] + rsbuf[3][nl];
            float sc = 1.0f / (1e-9f + tot);
            size_t orow = ((size_t)b * 2048 + n0 + nl) * 256;
            out[orow + (2 * j8 + 0) * 16 + t] = accv[s2][0][r] * sc;
            out[orow + (2 * j8 + 1) * 16 + t] = accv[s2][1][r] * sc;
        }
    }
}

extern "C" void kernel_launch(void* const* d_in, const int* in_sizes, int n_in,
                              void* d_out, int out_size, void* d_ws, size_t ws_size,
                              hipStream_t stream) {
    (void)in_sizes; (void)n_in; (void)out_size; (void)ws_size;
    const float* x  = (const float*)d_in[0];
    const float* Wq = (const float*)d_in[1];
    const float* Wk = (const float*)d_in[2];
    const float* Wv = (const float*)d_in[3];
    float* out = (float*)d_out;

    char* ws = (char*)d_ws;
    size_t off = 0;
    unsigned short* Wh = (unsigned short*)(ws + off); off += (size_t)384 * 256 * 2;
    unsigned short* Wl = (unsigned short*)(ws + off); off += (size_t)384 * 256 * 2;
    unsigned short* xh = (unsigned short*)(ws + off); off += (size_t)BB * NN * CC * 2;
    unsigned short* xl = (unsigned short*)(ws + off); off += (size_t)BB * NN * CC * 2;
    unsigned short* qh = (unsigned short*)(ws + off); off += (size_t)BB * NN * DKK * 2;
    unsigned short* ql = (unsigned short*)(ws + off); off += (size_t)BB * NN * DKK * 2;
    unsigned short* kh = (unsigned short*)(ws + off); off += (size_t)BB * NN * DKK * 2;
    unsigned short* kl = (unsigned short*)(ws + off); off += (size_t)BB * NN * DKK * 2;
    unsigned short* vT = (unsigned short*)(ws + off); off += (size_t)BB * DVV * NN * 2;
    float* cs = (float*)(ws + off);                   off += (size_t)BB * NN * 4;

    hipLaunchKernelGGL(k_wt,     dim3(384),         dim3(256),  0, stream, Wq, Wk, Wv, Wh, Wl);
    hipLaunchKernelGGL(k_split,  dim3(2048),        dim3(256),  0, stream, x, xh, xl);
    hipLaunchKernelGGL(k_vproj,  dim3(1024),        dim3(256),  0, stream, xh, Wh, vT);
    hipLaunchKernelGGL(k_qkproj, dim3(1024),        dim3(256),  0, stream, xh, xl, Wh, Wl, qh, ql, kh, kl);
    hipLaunchKernelGGL(k_colsum, dim3(NN / 64, BB), dim3(1024), 0, stream, qh, ql, kh, kl, cs);
    hipLaunchKernelGGL(k_attn,   dim3(NN / 64, BB), dim3(1024), 0, stream, qh, ql, kh, kl, vT, cs, out);
}